// Round 4
// baseline (340.663 us; speedup 1.0000x reference)
//
#include <hip/hip_runtime.h>
#include <math.h>

#define Tn 64
#define Bn 128
#define MUc 0.1f
#define REGc 1e-6f

// ---- dynamic LDS layout (float offsets) ----
#define OG    0        // G dbuf [2][9216]
#define OQb   18432    // Q dbuf [2][576]
#define OFb   19584    // F dbuf [2][384]  (row-major [n][24])
#define OWb   20352    // W dbuf [2][192]  (row-major [c][24])
#define Oqv   20736    // q dbuf [2][24]
#define Ocv7  20784    // c copy wave7 [2][8]
#define Osv7  20800    // s copy wave7 [2][8]
#define Ocv8  20816    // c copy wave8 [2][8]
#define Osv8  20832    // s copy wave8 [2][8]
#define OFT   20848    // F^T [24][16] (current step)
#define OVFT  21232    // (V F)^T [24][16]
#define OWT   21616    // W^T [24][8]
#define OWS   21808    // (sc*W)^T [24][8]
#define OQh   22000    // Qh [576] (full, mirror-filled)
#define OAs   22576    // V carry [16][16] symmetric
#define Ovls  22832    // v carry [16]
#define Oqh2  22848    // qh [24]
#define OK2   22880    // per t: KT[c<16][a<8] at c*8+a, kt[a] at 128+a  -> [64][136]
#define SMEMF 31584    // floats = 126336 bytes
// forward-pass overlay (inside dead G region)
#define OMs   0        // [2][272]
#define Obs   544      // [2][16]
#define Odx   576      // [65][16]
#define OFr   1616     // [4][384]

#define AS1C(p) ((const __attribute__((address_space(1))) void*)(p))
#define AS3(p)  ((__attribute__((address_space(3))) void*)(p))
#define GLD16(gp, lp) __builtin_amdgcn_global_load_lds(AS1C(gp), AS3(lp), 16, 0, 0)
#define GLD4(gp, lp)  __builtin_amdgcn_global_load_lds(AS1C(gp), AS3(lp), 4, 0, 0)

#define VMW(n) asm volatile("s_waitcnt vmcnt(" #n ")" ::: "memory")
#define BARRIER() do { \
  asm volatile("s_waitcnt lgkmcnt(0)" ::: "memory"); \
  __builtin_amdgcn_s_barrier(); \
  asm volatile("" ::: "memory"); } while (0)

__global__ __launch_bounds__(576, 1) void ipddp_kernel(
    const float* __restrict__ Qg, const float* __restrict__ qg,
    const float* __restrict__ Fg, const float* __restrict__ Gg,
    const float* __restrict__ Wg, const float* __restrict__ cg,
    const float* __restrict__ sg, const float* __restrict__ VTg,
    const float* __restrict__ vTg, const float* __restrict__ x0g,
    const float* __restrict__ xnomg, const float* __restrict__ unomg,
    float* __restrict__ outg)
{
  extern __shared__ float sm[];
  const int b   = blockIdx.x;
  const int tid = threadIdx.x;
  const int wv  = tid >> 6;
  const int ln  = tid & 63;

  // per-thread triangular maps (held in registers for the whole kernel)
  int ti = 0, tj = 0;            // 24-tri, threads 0..299
  if (tid < 300) { int idx = tid, r = 0; while (idx >= 24 - r) { idx -= 24 - r; ++r; } ti = r; tj = r + idx; }
  int pn = 0, pm = 0;            // 16-tri, threads 64..199
  if (tid >= 64 && tid < 200) { int idx = tid - 64, r = 0; while (idx >= 16 - r) { idx -= 16 - r; ++r; } pn = r; pm = r + idx; }

  // async-stage inputs for timestep tsrc into parity buffer nx.
  // Per-wave VMEM issue counts (order matters for counted vmcnt!):
  //   wave 0: [G*4, Q]                         = 5
  //   waves 1-6: [F_chunk, G*4, Q]             = 6
  //   wave 7: [W0, W1, c, s, G*4, Q]           = 9
  //   wave 8: [W2, c, s, q, G*4, Q]            = 9
  auto STAGE = [&](int tsrc, int nx) {
    const size_t pb = (size_t)(tsrc * Bn + b);
    if (wv >= 1 && wv <= 6) {
      GLD4(Fg + pb * 384 + (wv - 1) * 64 + ln, sm + OFb + nx * 384 + (wv - 1) * 64);
    } else if (wv == 7) {
      GLD4(Wg + pb * 192 + ln,      sm + OWb + nx * 192);
      GLD4(Wg + pb * 192 + 64 + ln, sm + OWb + nx * 192 + 64);
      if (ln < 8) GLD4(cg + pb * 8 + ln, sm + Ocv7 + nx * 8);
      if (ln < 8) GLD4(sg + pb * 8 + ln, sm + Osv7 + nx * 8);
    } else if (wv == 8) {
      GLD4(Wg + pb * 192 + 128 + ln, sm + OWb + nx * 192 + 128);
      if (ln < 8)  GLD4(cg + pb * 8 + ln,  sm + Ocv8 + nx * 8);
      if (ln < 8)  GLD4(sg + pb * 8 + ln,  sm + Osv8 + nx * 8);
      if (ln < 24) GLD4(qg + pb * 24 + ln, sm + Oqv + nx * 24);
    }
#pragma unroll
    for (int r = 0; r < 4; ++r)
      GLD16(Gg + pb * 9216 + (size_t)(wv * 4 + r) * 256 + ln * 4,
            sm + OG + nx * 9216 + (wv * 4 + r) * 256);
    GLD4(Qg + pb * 576 + wv * 64 + ln, sm + OQb + nx * 576 + wv * 64);
  };

  // ---------------- prologue: stage t=63 into buf1, prep ----------------
  STAGE(Tn - 1, 1);
  asm volatile("s_waitcnt vmcnt(0)" ::: "memory");
  BARRIER();
  if (tid < 256) sm[OAs + tid] = VTg[(size_t)b * 256 + tid];        // V sym
  if (tid < 192) {
    const int c = tid / 24, i2 = tid - c * 24;
    const float w  = sm[OWb + 192 + tid];
    const float cc = sm[Ocv7 + 8 + c], ss = sm[Osv7 + 8 + c];
    sm[OWT + i2 * 8 + c] = w;
    sm[OWS + i2 * 8 + c] = w * (ss / cc);
  }
  if (tid >= 192 && tid < 576) {
    const int src = tid - 192;
    sm[OFT + (src % 24) * 16 + src / 24] = sm[OFb + 384 + src];
  }
  if (tid >= 160 && tid < 176) sm[Ovls + (tid - 160)] = vTg[(size_t)b * 16 + (tid - 160)];
  BARRIER();

  // ---------------- backward scan ----------------
#pragma unroll 1
  for (int t = Tn - 1; t >= 0; --t) {
    const int P = t & 1, nx = P ^ 1;
    const float* Gb = sm + OG + P * 9216;
    const float* Qb = sm + OQb + P * 576;

    // ---- S1: issue DMA for t-1; compute VFT = (V F)^T ----
    if (t > 0) STAGE(t - 1, nx);
    if (tid >= 192 && tid < 384) {
      const int idx = tid - 192;
      const int n = idx & 15, j0 = (idx >> 4) * 2;
      float s0 = 0.f, s1 = 0.f;
#pragma unroll
      for (int r = 0; r < 4; ++r) {
        const float4 av = ((const float4*)(sm + OAs + n * 16))[r];
        const float4 x0 = ((const float4*)(sm + OFT + j0 * 16))[r];
        const float4 x1 = ((const float4*)(sm + OFT + (j0 + 1) * 16))[r];
        s0 = fmaf(av.x, x0.x, fmaf(av.y, x0.y, fmaf(av.z, x0.z, fmaf(av.w, x0.w, s0))));
        s1 = fmaf(av.x, x1.x, fmaf(av.y, x1.y, fmaf(av.z, x1.z, fmaf(av.w, x1.w, s1))));
      }
      sm[OVFT + j0 * 16 + n]       = s0;
      sm[OVFT + (j0 + 1) * 16 + n] = s1;
    }
    // pre-B1: guarantee timestep t's data fully arrived (leave t-1's in flight)
    if (t > 0) {
      if (wv == 0) VMW(5); else if (wv < 7) VMW(6); else VMW(9);
    } else {
      asm volatile("s_waitcnt vmcnt(0)" ::: "memory");
    }
    BARRIER();   // B1

    // ---- P2: Qh upper-triangle (+mirror) and qh ----
    if (tid < 300) {
      float acc = Qb[ti * 24 + tj];
#pragma unroll
      for (int r = 0; r < 4; ++r) {
        const float4 x = ((const float4*)(sm + OFT + ti * 16))[r];
        const float4 y = ((const float4*)(sm + OVFT + tj * 16))[r];
        acc = fmaf(x.x, y.x, fmaf(x.y, y.y, fmaf(x.z, y.z, fmaf(x.w, y.w, acc))));
      }
      const float4 v0 = ((const float4*)(sm + Ovls))[0];
      const float4 v1 = ((const float4*)(sm + Ovls))[1];
      const float4 v2 = ((const float4*)(sm + Ovls))[2];
      const float4 v3 = ((const float4*)(sm + Ovls))[3];
      const float* gp = Gb + ti * 24 + tj;
      acc = fmaf(v0.x, gp[0],    acc); acc = fmaf(v0.y, gp[576],  acc);
      acc = fmaf(v0.z, gp[1152], acc); acc = fmaf(v0.w, gp[1728], acc);
      acc = fmaf(v1.x, gp[2304], acc); acc = fmaf(v1.y, gp[2880], acc);
      acc = fmaf(v1.z, gp[3456], acc); acc = fmaf(v1.w, gp[4032], acc);
      acc = fmaf(v2.x, gp[4608], acc); acc = fmaf(v2.y, gp[5184], acc);
      acc = fmaf(v2.z, gp[5760], acc); acc = fmaf(v2.w, gp[6336], acc);
      acc = fmaf(v3.x, gp[6912], acc); acc = fmaf(v3.y, gp[7488], acc);
      acc = fmaf(v3.z, gp[8064], acc); acc = fmaf(v3.w, gp[8640], acc);
      {
        const float4 x0 = ((const float4*)(sm + OWT + ti * 8))[0];
        const float4 x1 = ((const float4*)(sm + OWT + ti * 8))[1];
        const float4 y0 = ((const float4*)(sm + OWS + tj * 8))[0];
        const float4 y1 = ((const float4*)(sm + OWS + tj * 8))[1];
        acc = fmaf(-x0.x, y0.x, acc); acc = fmaf(-x0.y, y0.y, acc);
        acc = fmaf(-x0.z, y0.z, acc); acc = fmaf(-x0.w, y0.w, acc);
        acc = fmaf(-x1.x, y1.x, acc); acc = fmaf(-x1.y, y1.y, acc);
        acc = fmaf(-x1.z, y1.z, acc); acc = fmaf(-x1.w, y1.w, acc);
      }
      sm[OQh + ti * 24 + tj] = acc;
      sm[OQh + tj * 24 + ti] = acc;
    } else if (tid >= 320 && tid < 344) {
      const int i2 = tid - 320;
      float a = sm[Oqv + P * 24 + i2];
#pragma unroll
      for (int r = 0; r < 4; ++r) {
        const float4 x = ((const float4*)(sm + OFT + i2 * 16))[r];
        const float4 y = ((const float4*)(sm + Ovls))[r];
        a = fmaf(x.x, y.x, fmaf(x.y, y.y, fmaf(x.z, y.z, fmaf(x.w, y.w, a))));
      }
#pragma unroll
      for (int c = 0; c < 8; ++c) {
        const float cc = sm[Ocv7 + P * 8 + c], ss = sm[Osv7 + P * 8 + c];
        const float w2 = ss - fmaf(ss, cc, MUc) / cc;
        a = fmaf(sm[OWb + P * 192 + c * 24 + i2], w2, a);
      }
      sm[Oqh2 + i2] = a;
    }
    // pre-B2: guarantee F/W/c/s of t-1 arrived (for P3-window prep)
    if (t > 0) {
      if (wv >= 1 && wv < 7) VMW(5);
      else if (wv == 7) VMW(5);
      else if (wv == 8) VMW(6);
    }
    BARRIER();   // B2

    // ---- P3: wave0 Gauss-Jordan; waves 1-6 F-transpose; 7-8 WT/WS prep ----
    if (wv == 0) {
      float colv[8];
      const int cl = (ln < 8) ? (16 + ln) : ((ln < 24) ? (ln - 8) : 0);
#pragma unroll
      for (int a = 0; a < 8; ++a) colv[a] = 0.f;
      if (ln < 24) {
#pragma unroll
        for (int a = 0; a < 8; ++a) colv[a] = sm[OQh + (16 + a) * 24 + cl];
        if (ln < 8) colv[ln] += REGc;
      } else if (ln == 24) {
#pragma unroll
        for (int a = 0; a < 8; ++a) colv[a] = sm[Oqh2 + 16 + a];
      }
#pragma unroll
      for (int k = 0; k < 8; ++k) {
        const float pk = __shfl(colv[k], k);
        const float inv = 1.0f / pk;
        colv[k] *= inv;
#pragma unroll
        for (int a2 = 0; a2 < 8; ++a2) {
          if (a2 == k) continue;
          const float m = __shfl(colv[a2], k);
          colv[a2] = fmaf(-m, colv[k], colv[a2]);
        }
      }
      float* kbase = sm + OK2 + t * 136;
      if (ln >= 8 && ln < 24) {
        float4 w0, w1;
        w0.x = -colv[0]; w0.y = -colv[1]; w0.z = -colv[2]; w0.w = -colv[3];
        w1.x = -colv[4]; w1.y = -colv[5]; w1.z = -colv[6]; w1.w = -colv[7];
        ((float4*)(kbase + (ln - 8) * 8))[0] = w0;
        ((float4*)(kbase + (ln - 8) * 8))[1] = w1;
      } else if (ln == 24) {
        float4 w0, w1;
        w0.x = -colv[0]; w0.y = -colv[1]; w0.z = -colv[2]; w0.w = -colv[3];
        w1.x = -colv[4]; w1.y = -colv[5]; w1.z = -colv[6]; w1.w = -colv[7];
        ((float4*)(kbase + 128))[0] = w0;
        ((float4*)(kbase + 128))[1] = w1;
      }
      const float kt0 = -__shfl(colv[0], 24), kt1 = -__shfl(colv[1], 24);
      const float kt2 = -__shfl(colv[2], 24), kt3 = -__shfl(colv[3], 24);
      const float kt4 = -__shfl(colv[4], 24), kt5 = -__shfl(colv[5], 24);
      const float kt6 = -__shfl(colv[6], 24), kt7 = -__shfl(colv[7], 24);
      if (ln < 16) {
        float a = sm[Oqh2 + ln];
        const float4 qa = ((const float4*)(sm + OQh + ln * 24 + 16))[0];
        const float4 qb2 = ((const float4*)(sm + OQh + ln * 24 + 16))[1];
        a = fmaf(qa.x, kt0, a); a = fmaf(qa.y, kt1, a);
        a = fmaf(qa.z, kt2, a); a = fmaf(qa.w, kt3, a);
        a = fmaf(qb2.x, kt4, a); a = fmaf(qb2.y, kt5, a);
        a = fmaf(qb2.z, kt6, a); a = fmaf(qb2.w, kt7, a);
        sm[Ovls + ln] = a;
      }
    } else if (wv <= 6) {
      const int src = (wv - 1) * 64 + ln;
      const int n = src / 24, d = src - n * 24;
      sm[OFT + d * 16 + n] = sm[OFb + nx * 384 + src];
    } else if (wv == 7) {
#pragma unroll
      for (int r = 0; r < 2; ++r) {
        const int src = r * 64 + ln;
        const int c = src / 24, i2 = src - c * 24;
        const float w  = sm[OWb + nx * 192 + src];
        const float cc = sm[Ocv7 + nx * 8 + c], ss = sm[Osv7 + nx * 8 + c];
        sm[OWT + i2 * 8 + c] = w;
        sm[OWS + i2 * 8 + c] = w * (ss / cc);
      }
    } else {
      const int src = 128 + ln;
      const int c = src / 24, i2 = src - c * 24;
      const float w  = sm[OWb + nx * 192 + src];
      const float cc = sm[Ocv8 + nx * 8 + c], ss = sm[Osv8 + nx * 8 + c];
      sm[OWT + i2 * 8 + c] = w;
      sm[OWS + i2 * 8 + c] = w * (ss / cc);
    }
    BARRIER();   // B3

    // ---- P4: V' = Qxx + Qxu*K (Schur), 16-tri + mirror ----
    if (tid >= 64 && tid < 200) {
      float acc = sm[OQh + pn * 24 + pm];
      const float4 qa  = ((const float4*)(sm + OQh + pn * 24 + 16))[0];
      const float4 qb2 = ((const float4*)(sm + OQh + pn * 24 + 16))[1];
      const float4 k0 = ((const float4*)(sm + OK2 + t * 136 + pm * 8))[0];
      const float4 k1 = ((const float4*)(sm + OK2 + t * 136 + pm * 8))[1];
      acc = fmaf(qa.x, k0.x, acc); acc = fmaf(qa.y, k0.y, acc);
      acc = fmaf(qa.z, k0.z, acc); acc = fmaf(qa.w, k0.w, acc);
      acc = fmaf(qb2.x, k1.x, acc); acc = fmaf(qb2.y, k1.y, acc);
      acc = fmaf(qb2.z, k1.z, acc); acc = fmaf(qb2.w, k1.w, acc);
      sm[OAs + pn * 16 + pm] = acc;
      sm[OAs + pm * 16 + pn] = acc;
    }
    BARRIER();   // B4
  }

  // ---------------- forward rollout (overlay in dead G region) ----------------
  float rfA0 = 0.f, rfA1 = 0.f, rfB0 = 0.f, rfB1 = 0.f;
  if (tid >= 384) {
    const int j = tid - 384;
#pragma unroll
    for (int slot = 0; slot < 3; ++slot) {
      sm[OFr + slot * 384 + 2 * j]     = Fg[(size_t)(slot * Bn + b) * 384 + 2 * j];
      sm[OFr + slot * 384 + 2 * j + 1] = Fg[(size_t)(slot * Bn + b) * 384 + 2 * j + 1];
    }
    rfA0 = Fg[(size_t)(3 * Bn + b) * 384 + 2 * j];
    rfA1 = Fg[(size_t)(3 * Bn + b) * 384 + 2 * j + 1];
    rfB0 = Fg[(size_t)(4 * Bn + b) * 384 + 2 * j];
    rfB1 = Fg[(size_t)(4 * Bn + b) * 384 + 2 * j + 1];
  }
  if (tid < 16) sm[Odx + tid] = x0g[(size_t)b * 16 + tid] - xnomg[(size_t)b * 16 + tid];
  BARRIER();

  // M0 = fx0 + fu0*K0, b0 = fu0*k0
  if (tid >= 64 && tid < 320) {
    const int idx = tid - 64, i = idx >> 4, j = idx & 15;
    const float* fr = sm + OFr + i * 24;
    const float4 k0 = ((const float4*)(sm + OK2 + j * 8))[0];
    const float4 k1 = ((const float4*)(sm + OK2 + j * 8))[1];
    float a = fr[j];
    a = fmaf(fr[16], k0.x, a); a = fmaf(fr[17], k0.y, a);
    a = fmaf(fr[18], k0.z, a); a = fmaf(fr[19], k0.w, a);
    a = fmaf(fr[20], k1.x, a); a = fmaf(fr[21], k1.y, a);
    a = fmaf(fr[22], k1.z, a); a = fmaf(fr[23], k1.w, a);
    sm[OMs + i * 17 + j] = a;
  } else if (tid >= 320 && tid < 336) {
    const int i = tid - 320;
    const float* fr = sm + OFr + i * 24;
    float a = 0.f;
#pragma unroll
    for (int m = 0; m < 8; ++m) a = fmaf(fr[16 + m], sm[OK2 + 128 + m], a);
    sm[Obs + i] = a;
  }
  BARRIER();

#pragma unroll 1
  for (int t = 0; t < Tn; ++t) {
    const int cur = t & 1, nx2 = (t + 1) & 1;
    if (tid < 16) {
      const int i = tid;
      float a = sm[Obs + cur * 16 + i];
#pragma unroll
      for (int k2 = 0; k2 < 16; ++k2)
        a = fmaf(sm[OMs + cur * 272 + i * 17 + k2], sm[Odx + t * 16 + k2], a);
      sm[Odx + (t + 1) * 16 + i] = a;
    } else if (tid >= 64 && tid < 320) {
      if (t + 1 < Tn) {
        const int idx = tid - 64, i = idx >> 4, j = idx & 15;
        const float* fr = sm + OFr + ((t + 1) & 3) * 384 + i * 24;
        const float4 k0 = ((const float4*)(sm + OK2 + (t + 1) * 136 + j * 8))[0];
        const float4 k1 = ((const float4*)(sm + OK2 + (t + 1) * 136 + j * 8))[1];
        float a = fr[j];
        a = fmaf(fr[16], k0.x, a); a = fmaf(fr[17], k0.y, a);
        a = fmaf(fr[18], k0.z, a); a = fmaf(fr[19], k0.w, a);
        a = fmaf(fr[20], k1.x, a); a = fmaf(fr[21], k1.y, a);
        a = fmaf(fr[22], k1.z, a); a = fmaf(fr[23], k1.w, a);
        sm[OMs + nx2 * 272 + i * 17 + j] = a;
      }
    } else if (tid >= 320 && tid < 336) {
      if (t + 1 < Tn) {
        const int i = tid - 320;
        const float* fr = sm + OFr + ((t + 1) & 3) * 384 + i * 24;
        float a = 0.f;
#pragma unroll
        for (int m = 0; m < 8; ++m) a = fmaf(fr[16 + m], sm[OK2 + (t + 1) * 136 + 128 + m], a);
        sm[Obs + nx2 * 16 + i] = a;
      }
    } else if (tid >= 384) {
      const int j = tid - 384;
      if (t + 3 < Tn) {
        sm[OFr + ((t + 3) & 3) * 384 + 2 * j]     = rfA0;
        sm[OFr + ((t + 3) & 3) * 384 + 2 * j + 1] = rfA1;
      }
      rfA0 = rfB0; rfA1 = rfB1;
      if (t + 5 < Tn) {
        rfB0 = Fg[(size_t)((t + 5) * Bn + b) * 384 + 2 * j];
        rfB1 = Fg[(size_t)((t + 5) * Bn + b) * 384 + 2 * j + 1];
      }
    }
    BARRIER();
  }

  // du_t = K_t dx_t + k_t for all t in parallel
  if (tid < 512) {
    const int tt = tid >> 3, m = tid & 7;
    const float* kb = sm + OK2 + tt * 136;
    float a = kb[128 + m];
#pragma unroll
    for (int n = 0; n < 16; ++n) a = fmaf(kb[n * 8 + m], sm[Odx + tt * 16 + n], a);
    const size_t o = (size_t)(tt * Bn + b) * 8 + m;
    outg[o] = unomg[o] + a;
  }
}

extern "C" void kernel_launch(void* const* d_in, const int* in_sizes, int n_in,
                              void* d_out, int out_size, void* d_ws, size_t ws_size,
                              hipStream_t stream) {
  (void)in_sizes; (void)n_in; (void)out_size; (void)d_ws; (void)ws_size;
  const float* Qg    = (const float*)d_in[0];
  const float* qg    = (const float*)d_in[1];
  const float* Fg    = (const float*)d_in[2];
  const float* Gg    = (const float*)d_in[3];
  const float* Wg    = (const float*)d_in[4];
  const float* cg    = (const float*)d_in[5];
  const float* sg    = (const float*)d_in[6];
  const float* VTg   = (const float*)d_in[7];
  const float* vTg   = (const float*)d_in[8];
  const float* x0g   = (const float*)d_in[9];
  const float* xnomg = (const float*)d_in[10];
  const float* unomg = (const float*)d_in[11];
  float* outg = (float*)d_out;

  (void)hipFuncSetAttribute((const void*)ipddp_kernel,
                            hipFuncAttributeMaxDynamicSharedMemorySize,
                            SMEMF * 4);
  ipddp_kernel<<<dim3(Bn), dim3(576), SMEMF * 4, stream>>>(
      Qg, qg, Fg, Gg, Wg, cg, sg, VTg, vTg, x0g, xnomg, unomg, outg);
}

// Round 5
// 283.035 us; speedup vs baseline: 1.2036x; 1.2036x over previous
//
#include <hip/hip_runtime.h>
#include <math.h>

#define Tn 64
#define Bn 128
#define MUc 0.1f
#define REGc 1e-6f

// ---- dynamic LDS layout (float offsets) ----
// All per-lane-indexed tiles use padded, float4-aligned, non-pow2 strides:
// 20 (gcd 4 w/ 32 banks), 12, 28 — kills the R4 bank-conflict regression.
#define OG    0        // G dbuf [2][9216]
#define OQb   18432    // Q dbuf [2][576]
#define OFb   19584    // F dbuf [2][384]  (row-major [n][24])
#define OWb   20352    // W dbuf [2][192]  (row-major [c][24])
#define Oqv   20736    // q dbuf [2][24]
#define Ocv7  20784    // c copy wave7 [2][8]
#define Osv7  20800    // s copy wave7 [2][8]
#define Ocv8  20816    // c copy wave8 [2][8]
#define Osv8  20832    // s copy wave8 [2][8]
#define OFT   20848    // F^T [24][pad20]
#define OVFT  21328    // (V F)^T [24][pad20]
#define OWT   21808    // W^T [24][pad12]
#define OWS   22096    // (sc*W)^T [24][pad12]
#define OQh   22384    // Qh [24][pad28] (full, mirror-filled)
#define OAs   23056    // V carry [16][pad20] symmetric
#define Ovls  23376    // v carry [16]
#define Oqh2  23392    // qh [24]
#define OK2   23416    // per t (stride 200): KT[c<16] at c*12 (8 used), kt at 192
#define SMEMF 36224    // floats = 144896 bytes
// forward-pass overlay (inside dead G region)
#define OMs   0        // [2][272]
#define Obs   544      // [2][16]
#define Odx   576      // [65][16]
#define OFr   1616     // [4][384]

#define AS1C(p) ((const __attribute__((address_space(1))) void*)(p))
#define AS3(p)  ((__attribute__((address_space(3))) void*)(p))
#define GLD16(gp, lp) __builtin_amdgcn_global_load_lds(AS1C(gp), AS3(lp), 16, 0, 0)
#define GLD4(gp, lp)  __builtin_amdgcn_global_load_lds(AS1C(gp), AS3(lp), 4, 0, 0)

#define VMW(n) asm volatile("s_waitcnt vmcnt(" #n ")" ::: "memory")
#define BARRIER() do { \
  asm volatile("s_waitcnt lgkmcnt(0)" ::: "memory"); \
  __builtin_amdgcn_s_barrier(); \
  asm volatile("" ::: "memory"); } while (0)

__global__ __launch_bounds__(576, 1) void ipddp_kernel(
    const float* __restrict__ Qg, const float* __restrict__ qg,
    const float* __restrict__ Fg, const float* __restrict__ Gg,
    const float* __restrict__ Wg, const float* __restrict__ cg,
    const float* __restrict__ sg, const float* __restrict__ VTg,
    const float* __restrict__ vTg, const float* __restrict__ x0g,
    const float* __restrict__ xnomg, const float* __restrict__ unomg,
    float* __restrict__ outg)
{
  extern __shared__ float sm[];
  const int b   = blockIdx.x;
  const int tid = threadIdx.x;
  const int wv  = tid >> 6;
  const int ln  = tid & 63;

  // per-thread triangular maps
  int ti = 0, tj = 0;            // 24-tri, threads 0..299
  if (tid < 300) { int idx = tid, r = 0; while (idx >= 24 - r) { idx -= 24 - r; ++r; } ti = r; tj = r + idx; }
  int pn = 0, pm = 0;            // 16-tri, threads 64..199
  if (tid >= 64 && tid < 200) { int idx = tid - 64, r = 0; while (idx >= 16 - r) { idx -= 16 - r; ++r; } pn = r; pm = r + idx; }

  // async-stage inputs for timestep tsrc into parity buffer nx.
  // Per-wave VMEM issue counts: w0=5, w1-6=6, w7=9, w8=9.
  auto STAGE = [&](int tsrc, int nx) {
    const size_t pb = (size_t)(tsrc * Bn + b);
    if (wv >= 1 && wv <= 6) {
      GLD4(Fg + pb * 384 + (wv - 1) * 64 + ln, sm + OFb + nx * 384 + (wv - 1) * 64);
    } else if (wv == 7) {
      GLD4(Wg + pb * 192 + ln,      sm + OWb + nx * 192);
      GLD4(Wg + pb * 192 + 64 + ln, sm + OWb + nx * 192 + 64);
      if (ln < 8) GLD4(cg + pb * 8 + ln, sm + Ocv7 + nx * 8);
      if (ln < 8) GLD4(sg + pb * 8 + ln, sm + Osv7 + nx * 8);
    } else if (wv == 8) {
      GLD4(Wg + pb * 192 + 128 + ln, sm + OWb + nx * 192 + 128);
      if (ln < 8)  GLD4(cg + pb * 8 + ln,  sm + Ocv8 + nx * 8);
      if (ln < 8)  GLD4(sg + pb * 8 + ln,  sm + Osv8 + nx * 8);
      if (ln < 24) GLD4(qg + pb * 24 + ln, sm + Oqv + nx * 24);
    }
#pragma unroll
    for (int r = 0; r < 4; ++r)
      GLD16(Gg + pb * 9216 + (size_t)(wv * 4 + r) * 256 + ln * 4,
            sm + OG + nx * 9216 + (wv * 4 + r) * 256);
    GLD4(Qg + pb * 576 + wv * 64 + ln, sm + OQb + nx * 576 + wv * 64);
  };

  // ---------------- prologue: stage t=63 into buf1, prep ----------------
  STAGE(Tn - 1, 1);
  asm volatile("s_waitcnt vmcnt(0)" ::: "memory");
  BARRIER();
  if (tid < 256) {
    const int n = tid >> 4, m = tid & 15;
    sm[OAs + n * 20 + m] = VTg[(size_t)b * 256 + tid];
  }
  if (tid < 192) {
    const int c = tid / 24, i2 = tid - c * 24;
    const float w  = sm[OWb + 192 + tid];
    const float cc = sm[Ocv7 + 8 + c], ss = sm[Osv7 + 8 + c];
    sm[OWT + i2 * 12 + c] = w;
    sm[OWS + i2 * 12 + c] = w * (ss / cc);
  }
  if (tid >= 192 && tid < 576) {
    const int src = tid - 192;
    sm[OFT + (src % 24) * 20 + src / 24] = sm[OFb + 384 + src];
  }
  if (tid >= 160 && tid < 176) sm[Ovls + (tid - 160)] = vTg[(size_t)b * 16 + (tid - 160)];
  BARRIER();

  // ---------------- backward scan ----------------
#pragma unroll 1
  for (int t = Tn - 1; t >= 0; --t) {
    const int P = t & 1, nx = P ^ 1;
    const float* Gb = sm + OG + P * 9216;
    const float* Qb = sm + OQb + P * 576;

    // ---- S1: issue DMA for t-1; compute VFT = (V F)^T ----
    if (t > 0) STAGE(t - 1, nx);
    if (tid >= 192 && tid < 384) {
      const int idx = tid - 192;
      const int n = idx & 15, j0 = (idx >> 4) * 2;
      float s0 = 0.f, s1 = 0.f;
#pragma unroll
      for (int r = 0; r < 4; ++r) {
        const float4 av = ((const float4*)(sm + OAs + n * 20))[r];
        const float4 x0 = ((const float4*)(sm + OFT + j0 * 20))[r];
        const float4 x1 = ((const float4*)(sm + OFT + (j0 + 1) * 20))[r];
        s0 = fmaf(av.x, x0.x, fmaf(av.y, x0.y, fmaf(av.z, x0.z, fmaf(av.w, x0.w, s0))));
        s1 = fmaf(av.x, x1.x, fmaf(av.y, x1.y, fmaf(av.z, x1.z, fmaf(av.w, x1.w, s1))));
      }
      sm[OVFT + j0 * 20 + n]       = s0;
      sm[OVFT + (j0 + 1) * 20 + n] = s1;
    }
    // pre-B1: timestep t's data fully arrived (leave t-1's in flight)
    if (t > 0) {
      if (wv == 0) VMW(5); else if (wv < 7) VMW(6); else VMW(9);
    } else {
      asm volatile("s_waitcnt vmcnt(0)" ::: "memory");
    }
    BARRIER();   // B1

    // ---- P2: Qh upper-triangle (+mirror) and qh ----
    if (tid < 300) {
      float acc = Qb[ti * 24 + tj];
#pragma unroll
      for (int r = 0; r < 4; ++r) {
        const float4 x = ((const float4*)(sm + OFT + ti * 20))[r];
        const float4 y = ((const float4*)(sm + OVFT + tj * 20))[r];
        acc = fmaf(x.x, y.x, fmaf(x.y, y.y, fmaf(x.z, y.z, fmaf(x.w, y.w, acc))));
      }
      const float4 v0 = ((const float4*)(sm + Ovls))[0];
      const float4 v1 = ((const float4*)(sm + Ovls))[1];
      const float4 v2 = ((const float4*)(sm + Ovls))[2];
      const float4 v3 = ((const float4*)(sm + Ovls))[3];
      const float* gp = Gb + ti * 24 + tj;
      acc = fmaf(v0.x, gp[0],    acc); acc = fmaf(v0.y, gp[576],  acc);
      acc = fmaf(v0.z, gp[1152], acc); acc = fmaf(v0.w, gp[1728], acc);
      acc = fmaf(v1.x, gp[2304], acc); acc = fmaf(v1.y, gp[2880], acc);
      acc = fmaf(v1.z, gp[3456], acc); acc = fmaf(v1.w, gp[4032], acc);
      acc = fmaf(v2.x, gp[4608], acc); acc = fmaf(v2.y, gp[5184], acc);
      acc = fmaf(v2.z, gp[5760], acc); acc = fmaf(v2.w, gp[6336], acc);
      acc = fmaf(v3.x, gp[6912], acc); acc = fmaf(v3.y, gp[7488], acc);
      acc = fmaf(v3.z, gp[8064], acc); acc = fmaf(v3.w, gp[8640], acc);
      {
        const float4 x0 = ((const float4*)(sm + OWT + ti * 12))[0];
        const float4 x1 = ((const float4*)(sm + OWT + ti * 12))[1];
        const float4 y0 = ((const float4*)(sm + OWS + tj * 12))[0];
        const float4 y1 = ((const float4*)(sm + OWS + tj * 12))[1];
        acc = fmaf(-x0.x, y0.x, acc); acc = fmaf(-x0.y, y0.y, acc);
        acc = fmaf(-x0.z, y0.z, acc); acc = fmaf(-x0.w, y0.w, acc);
        acc = fmaf(-x1.x, y1.x, acc); acc = fmaf(-x1.y, y1.y, acc);
        acc = fmaf(-x1.z, y1.z, acc); acc = fmaf(-x1.w, y1.w, acc);
      }
      sm[OQh + ti * 28 + tj] = acc;
      sm[OQh + tj * 28 + ti] = acc;
    } else if (tid >= 320 && tid < 344) {
      const int i2 = tid - 320;
      float a = sm[Oqv + P * 24 + i2];
#pragma unroll
      for (int r = 0; r < 4; ++r) {
        const float4 x = ((const float4*)(sm + OFT + i2 * 20))[r];
        const float4 y = ((const float4*)(sm + Ovls))[r];
        a = fmaf(x.x, y.x, fmaf(x.y, y.y, fmaf(x.z, y.z, fmaf(x.w, y.w, a))));
      }
#pragma unroll
      for (int c = 0; c < 8; ++c) {
        const float cc = sm[Ocv7 + P * 8 + c], ss = sm[Osv7 + P * 8 + c];
        const float w2 = ss - fmaf(ss, cc, MUc) / cc;
        a = fmaf(sm[OWb + P * 192 + c * 24 + i2], w2, a);
      }
      sm[Oqh2 + i2] = a;
    }
    // pre-B2: F/W/c/s of t-1 arrived (for P3-window prep)
    if (t > 0) {
      if (wv >= 1 && wv < 7) VMW(5);
      else if (wv == 7) VMW(5);
      else if (wv == 8) VMW(6);
    }
    BARRIER();   // B2

    // ---- P3: wave0 Gauss-Jordan; waves 1-6 F-transpose; 7-8 WT/WS prep ----
    if (wv == 0) {
      float colv[8];
      const int cl = (ln < 8) ? (16 + ln) : ((ln < 24) ? (ln - 8) : 0);
#pragma unroll
      for (int a = 0; a < 8; ++a) colv[a] = 0.f;
      if (ln < 24) {
#pragma unroll
        for (int a = 0; a < 8; ++a) colv[a] = sm[OQh + (16 + a) * 28 + cl];
        if (ln < 8) colv[ln] += REGc;
      } else if (ln == 24) {
#pragma unroll
        for (int a = 0; a < 8; ++a) colv[a] = sm[Oqh2 + 16 + a];
      }
#pragma unroll
      for (int k = 0; k < 8; ++k) {
        const float pk = __shfl(colv[k], k);
        const float inv = 1.0f / pk;
        colv[k] *= inv;
#pragma unroll
        for (int a2 = 0; a2 < 8; ++a2) {
          if (a2 == k) continue;
          const float m = __shfl(colv[a2], k);
          colv[a2] = fmaf(-m, colv[k], colv[a2]);
        }
      }
      float* kbase = sm + OK2 + t * 200;
      if (ln >= 8 && ln < 24) {
        float4 w0, w1;
        w0.x = -colv[0]; w0.y = -colv[1]; w0.z = -colv[2]; w0.w = -colv[3];
        w1.x = -colv[4]; w1.y = -colv[5]; w1.z = -colv[6]; w1.w = -colv[7];
        ((float4*)(kbase + (ln - 8) * 12))[0] = w0;
        ((float4*)(kbase + (ln - 8) * 12))[1] = w1;
      } else if (ln == 24) {
        float4 w0, w1;
        w0.x = -colv[0]; w0.y = -colv[1]; w0.z = -colv[2]; w0.w = -colv[3];
        w1.x = -colv[4]; w1.y = -colv[5]; w1.z = -colv[6]; w1.w = -colv[7];
        ((float4*)(kbase + 192))[0] = w0;
        ((float4*)(kbase + 192))[1] = w1;
      }
      const float kt0 = -__shfl(colv[0], 24), kt1 = -__shfl(colv[1], 24);
      const float kt2 = -__shfl(colv[2], 24), kt3 = -__shfl(colv[3], 24);
      const float kt4 = -__shfl(colv[4], 24), kt5 = -__shfl(colv[5], 24);
      const float kt6 = -__shfl(colv[6], 24), kt7 = -__shfl(colv[7], 24);
      if (ln < 16) {
        float a = sm[Oqh2 + ln];
        const float4 qa  = ((const float4*)(sm + OQh + ln * 28 + 16))[0];
        const float4 qb2 = ((const float4*)(sm + OQh + ln * 28 + 16))[1];
        a = fmaf(qa.x, kt0, a); a = fmaf(qa.y, kt1, a);
        a = fmaf(qa.z, kt2, a); a = fmaf(qa.w, kt3, a);
        a = fmaf(qb2.x, kt4, a); a = fmaf(qb2.y, kt5, a);
        a = fmaf(qb2.z, kt6, a); a = fmaf(qb2.w, kt7, a);
        sm[Ovls + ln] = a;
      }
    } else if (wv <= 6) {
      const int src = (wv - 1) * 64 + ln;
      const int n = src / 24, d = src - n * 24;
      sm[OFT + d * 20 + n] = sm[OFb + nx * 384 + src];
    } else if (wv == 7) {
#pragma unroll
      for (int r = 0; r < 2; ++r) {
        const int src = r * 64 + ln;
        const int c = src / 24, i2 = src - c * 24;
        const float w  = sm[OWb + nx * 192 + src];
        const float cc = sm[Ocv7 + nx * 8 + c], ss = sm[Osv7 + nx * 8 + c];
        sm[OWT + i2 * 12 + c] = w;
        sm[OWS + i2 * 12 + c] = w * (ss / cc);
      }
    } else {
      const int src = 128 + ln;
      const int c = src / 24, i2 = src - c * 24;
      const float w  = sm[OWb + nx * 192 + src];
      const float cc = sm[Ocv8 + nx * 8 + c], ss = sm[Osv8 + nx * 8 + c];
      sm[OWT + i2 * 12 + c] = w;
      sm[OWS + i2 * 12 + c] = w * (ss / cc);
    }
    BARRIER();   // B3

    // ---- P4: V' = Qxx + Qxu*K (Schur), 16-tri + mirror ----
    if (tid >= 64 && tid < 200) {
      float acc = sm[OQh + pn * 28 + pm];
      const float4 qa  = ((const float4*)(sm + OQh + pn * 28 + 16))[0];
      const float4 qb2 = ((const float4*)(sm + OQh + pn * 28 + 16))[1];
      const float4 k0 = ((const float4*)(sm + OK2 + t * 200 + pm * 12))[0];
      const float4 k1 = ((const float4*)(sm + OK2 + t * 200 + pm * 12))[1];
      acc = fmaf(qa.x, k0.x, acc); acc = fmaf(qa.y, k0.y, acc);
      acc = fmaf(qa.z, k0.z, acc); acc = fmaf(qa.w, k0.w, acc);
      acc = fmaf(qb2.x, k1.x, acc); acc = fmaf(qb2.y, k1.y, acc);
      acc = fmaf(qb2.z, k1.z, acc); acc = fmaf(qb2.w, k1.w, acc);
      sm[OAs + pn * 20 + pm] = acc;
      sm[OAs + pm * 20 + pn] = acc;
    }
    BARRIER();   // B4
  }

  // ---------------- forward rollout (overlay in dead G region) ----------------
  float rfA0 = 0.f, rfA1 = 0.f, rfB0 = 0.f, rfB1 = 0.f;
  if (tid >= 384) {
    const int j = tid - 384;
#pragma unroll
    for (int slot = 0; slot < 3; ++slot) {
      sm[OFr + slot * 384 + 2 * j]     = Fg[(size_t)(slot * Bn + b) * 384 + 2 * j];
      sm[OFr + slot * 384 + 2 * j + 1] = Fg[(size_t)(slot * Bn + b) * 384 + 2 * j + 1];
    }
    rfA0 = Fg[(size_t)(3 * Bn + b) * 384 + 2 * j];
    rfA1 = Fg[(size_t)(3 * Bn + b) * 384 + 2 * j + 1];
    rfB0 = Fg[(size_t)(4 * Bn + b) * 384 + 2 * j];
    rfB1 = Fg[(size_t)(4 * Bn + b) * 384 + 2 * j + 1];
  }
  if (tid < 16) sm[Odx + tid] = x0g[(size_t)b * 16 + tid] - xnomg[(size_t)b * 16 + tid];
  BARRIER();

  // M0 = fx0 + fu0*K0, b0 = fu0*k0
  if (tid >= 64 && tid < 320) {
    const int idx = tid - 64, i = idx >> 4, j = idx & 15;
    const float* fr = sm + OFr + i * 24;
    const float4 k0 = ((const float4*)(sm + OK2 + j * 12))[0];
    const float4 k1 = ((const float4*)(sm + OK2 + j * 12))[1];
    float a = fr[j];
    a = fmaf(fr[16], k0.x, a); a = fmaf(fr[17], k0.y, a);
    a = fmaf(fr[18], k0.z, a); a = fmaf(fr[19], k0.w, a);
    a = fmaf(fr[20], k1.x, a); a = fmaf(fr[21], k1.y, a);
    a = fmaf(fr[22], k1.z, a); a = fmaf(fr[23], k1.w, a);
    sm[OMs + i * 17 + j] = a;
  } else if (tid >= 320 && tid < 336) {
    const int i = tid - 320;
    const float* fr = sm + OFr + i * 24;
    float a = 0.f;
#pragma unroll
    for (int m = 0; m < 8; ++m) a = fmaf(fr[16 + m], sm[OK2 + 192 + m], a);
    sm[Obs + i] = a;
  }
  BARRIER();

#pragma unroll 1
  for (int t = 0; t < Tn; ++t) {
    const int cur = t & 1, nx2 = (t + 1) & 1;
    if (tid < 16) {
      const int i = tid;
      float a = sm[Obs + cur * 16 + i];
#pragma unroll
      for (int k2 = 0; k2 < 16; ++k2)
        a = fmaf(sm[OMs + cur * 272 + i * 17 + k2], sm[Odx + t * 16 + k2], a);
      sm[Odx + (t + 1) * 16 + i] = a;
    } else if (tid >= 64 && tid < 320) {
      if (t + 1 < Tn) {
        const int idx = tid - 64, i = idx >> 4, j = idx & 15;
        const float* fr = sm + OFr + ((t + 1) & 3) * 384 + i * 24;
        const float4 k0 = ((const float4*)(sm + OK2 + (t + 1) * 200 + j * 12))[0];
        const float4 k1 = ((const float4*)(sm + OK2 + (t + 1) * 200 + j * 12))[1];
        float a = fr[j];
        a = fmaf(fr[16], k0.x, a); a = fmaf(fr[17], k0.y, a);
        a = fmaf(fr[18], k0.z, a); a = fmaf(fr[19], k0.w, a);
        a = fmaf(fr[20], k1.x, a); a = fmaf(fr[21], k1.y, a);
        a = fmaf(fr[22], k1.z, a); a = fmaf(fr[23], k1.w, a);
        sm[OMs + nx2 * 272 + i * 17 + j] = a;
      }
    } else if (tid >= 320 && tid < 336) {
      if (t + 1 < Tn) {
        const int i = tid - 320;
        const float* fr = sm + OFr + ((t + 1) & 3) * 384 + i * 24;
        float a = 0.f;
#pragma unroll
        for (int m = 0; m < 8; ++m) a = fmaf(fr[16 + m], sm[OK2 + (t + 1) * 200 + 192 + m], a);
        sm[Obs + nx2 * 16 + i] = a;
      }
    } else if (tid >= 384) {
      const int j = tid - 384;
      if (t + 3 < Tn) {
        sm[OFr + ((t + 3) & 3) * 384 + 2 * j]     = rfA0;
        sm[OFr + ((t + 3) & 3) * 384 + 2 * j + 1] = rfA1;
      }
      rfA0 = rfB0; rfA1 = rfB1;
      if (t + 5 < Tn) {
        rfB0 = Fg[(size_t)((t + 5) * Bn + b) * 384 + 2 * j];
        rfB1 = Fg[(size_t)((t + 5) * Bn + b) * 384 + 2 * j + 1];
      }
    }
    BARRIER();
  }

  // du_t = K_t dx_t + k_t for all t in parallel
  if (tid < 512) {
    const int tt = tid >> 3, m = tid & 7;
    const float* kb = sm + OK2 + tt * 200;
    float a = kb[192 + m];
#pragma unroll
    for (int n = 0; n < 16; ++n) a = fmaf(kb[n * 12 + m], sm[Odx + tt * 16 + n], a);
    const size_t o = (size_t)(tt * Bn + b) * 8 + m;
    outg[o] = unomg[o] + a;
  }
}

extern "C" void kernel_launch(void* const* d_in, const int* in_sizes, int n_in,
                              void* d_out, int out_size, void* d_ws, size_t ws_size,
                              hipStream_t stream) {
  (void)in_sizes; (void)n_in; (void)out_size; (void)d_ws; (void)ws_size;
  const float* Qg    = (const float*)d_in[0];
  const float* qg    = (const float*)d_in[1];
  const float* Fg    = (const float*)d_in[2];
  const float* Gg    = (const float*)d_in[3];
  const float* Wg    = (const float*)d_in[4];
  const float* cg    = (const float*)d_in[5];
  const float* sg    = (const float*)d_in[6];
  const float* VTg   = (const float*)d_in[7];
  const float* vTg   = (const float*)d_in[8];
  const float* x0g   = (const float*)d_in[9];
  const float* xnomg = (const float*)d_in[10];
  const float* unomg = (const float*)d_in[11];
  float* outg = (float*)d_out;

  (void)hipFuncSetAttribute((const void*)ipddp_kernel,
                            hipFuncAttributeMaxDynamicSharedMemorySize,
                            SMEMF * 4);
  ipddp_kernel<<<dim3(Bn), dim3(576), SMEMF * 4, stream>>>(
      Qg, qg, Fg, Gg, Wg, cg, sg, VTg, vTg, x0g, xnomg, unomg, outg);
}